// Round 9
// baseline (164.644 us; speedup 1.0000x reference)
//
#include <hip/hip_runtime.h>

// ---------------------------------------------------------------------------
// T5 cross-attention fused pipeline for MI355X (gfx950)  — round 9
// B=2, Q=KV=2048, D_MODEL=1024, H=16, D=64
// attn: KVBLK=64 (LDS 32KB -> 4 blocks/CU). GEMM: BK=32 64B-pitch
// (conflict-free frag reads, m97 layout) + dbuf, launch_bounds(256,4);
// gemm_o: 64x128 tile -> 512 blocks.
// ---------------------------------------------------------------------------

typedef __attribute__((ext_vector_type(8))) short  s16x8;   // 8 bf16 (A/B frag)
typedef __attribute__((ext_vector_type(4))) float  f32x4;   // C/D frag
typedef __attribute__((ext_vector_type(4))) int    i32x4;

#define LOG2E 1.4426950408889634f
#define EXP2(x) __builtin_amdgcn_exp2f(x)

__device__ __forceinline__ unsigned short f2bf(float f) {
  unsigned int u = __builtin_bit_cast(unsigned int, f);
  return (unsigned short)((u + 0x7FFFu + ((u >> 16) & 1u)) >> 16);  // RNE
}

__device__ __forceinline__ unsigned cvtpk(float lo, float hi) {
  unsigned r;
  asm("v_cvt_pk_bf16_f32 %0, %1, %2" : "=v"(r) : "v"(lo), "v"(hi));
  return r;
}

__device__ __forceinline__ void gload16(const void* g, void* l) {
  __builtin_amdgcn_global_load_lds(
      (const __attribute__((address_space(1))) unsigned int*)g,
      (__attribute__((address_space(3))) unsigned int*)l, 16, 0, 0);
}

// ---------------------------------------------------------------------------
// Transpose-cast x4 in one dispatch: out[n][k] = bf16(in[k][n]), 1024x1024
// ---------------------------------------------------------------------------
__global__ __launch_bounds__(256) void k_transpose4(
    const float* __restrict__ a0, const float* __restrict__ a1,
    const float* __restrict__ a2, const float* __restrict__ a3,
    unsigned short* __restrict__ o0, unsigned short* __restrict__ o1,
    unsigned short* __restrict__ o2, unsigned short* __restrict__ o3) {
  int z = blockIdx.z;
  const float* in = (z == 0) ? a0 : (z == 1) ? a1 : (z == 2) ? a2 : a3;
  unsigned short* out = (z == 0) ? o0 : (z == 1) ? o1 : (z == 2) ? o2 : o3;
  __shared__ float tile[64][65];
  int t = threadIdx.x;
  int tx = t & 15, ty = t >> 4;
  int r0 = blockIdx.y * 64, c0 = blockIdx.x * 64;
#pragma unroll
  for (int p = 0; p < 4; ++p) {
    int r = p * 16 + ty;
    float4 v = *reinterpret_cast<const float4*>(in + (size_t)(r0 + r) * 1024 + c0 + tx * 4);
    tile[r][tx * 4 + 0] = v.x; tile[r][tx * 4 + 1] = v.y;
    tile[r][tx * 4 + 2] = v.z; tile[r][tx * 4 + 3] = v.w;
  }
  __syncthreads();
#pragma unroll
  for (int p = 0; p < 4; ++p) {
    int c = p * 16 + ty;
    unsigned int lo = (unsigned int)f2bf(tile[tx * 4 + 0][c]) |
                      ((unsigned int)f2bf(tile[tx * 4 + 1][c]) << 16);
    unsigned int hi = (unsigned int)f2bf(tile[tx * 4 + 2][c]) |
                      ((unsigned int)f2bf(tile[tx * 4 + 3][c]) << 16);
    uint2 pk2; pk2.x = lo; pk2.y = hi;
    *reinterpret_cast<uint2*>(out + (size_t)(c0 + c) * 1024 + r0 + tx * 4) = pk2;
  }
}

// ---------------------------------------------------------------------------
// RMSNorm + cast to bf16, scaled by log2(e) (feeds ONLY the Q projection ->
// QK^T scores land in the exp2 domain for free).
// ---------------------------------------------------------------------------
__global__ __launch_bounds__(256) void k_rmsnorm(
    const float* __restrict__ hs, const float* __restrict__ w,
    unsigned short* __restrict__ out) {
  int row = blockIdx.x, t = threadIdx.x;
  float4 v = *reinterpret_cast<const float4*>(hs + (size_t)row * 1024 + t * 4);
  float s = v.x * v.x + v.y * v.y + v.z * v.z + v.w * v.w;
#pragma unroll
  for (int m = 1; m < 64; m <<= 1) s += __shfl_xor(s, m);
  __shared__ float ps[4];
  if ((t & 63) == 0) ps[t >> 6] = s;
  __syncthreads();
  float tot = ps[0] + ps[1] + ps[2] + ps[3];
  float sc = rsqrtf(tot * (1.0f / 1024.0f) + 1e-6f) * LOG2E;
  float4 wv = *reinterpret_cast<const float4*>(w + t * 4);
  unsigned int lo = (unsigned int)f2bf(v.x * sc * wv.x) |
                    ((unsigned int)f2bf(v.y * sc * wv.y) << 16);
  unsigned int hi = (unsigned int)f2bf(v.z * sc * wv.z) |
                    ((unsigned int)f2bf(v.w * sc * wv.w) << 16);
  uint2 pk2; pk2.x = lo; pk2.y = hi;
  *reinterpret_cast<uint2*>(out + (size_t)row * 1024 + t * 4) = pk2;
}

// ---------------------------------------------------------------------------
// Plain f32 -> bf16 cast
// ---------------------------------------------------------------------------
__global__ __launch_bounds__(256) void k_cast(
    const float* __restrict__ in, unsigned short* __restrict__ out, int n4) {
  int i = blockIdx.x * 256 + threadIdx.x;
  int stride = gridDim.x * 256;
  for (; i < n4; i += stride) {
    float4 v = *reinterpret_cast<const float4*>(in + (size_t)i * 4);
    unsigned int lo = (unsigned int)f2bf(v.x) | ((unsigned int)f2bf(v.y) << 16);
    unsigned int hi = (unsigned int)f2bf(v.z) | ((unsigned int)f2bf(v.w) << 16);
    uint2 pk2; pk2.x = lo; pk2.y = hi;
    *reinterpret_cast<uint2*>(out + (size_t)i * 4) = pk2;
  }
}

// ---------------------------------------------------------------------------
// GEMM: C[M,N] = A[M,K] * Bt[N,K]^T  (N-tile always 128, K=1024, bf16 in)
// BM = 128 (qkv) or 64 (gemm_o). BK=32, 64B row pitch (contiguous frag reads,
// no bank conflicts), double-buffered, launch_bounds(256,4).
// mode 0: bf16 out; mode 1: bf16 out transposed to vT [b][h][d][2048];
// mode 2: f32 out + residual
// ---------------------------------------------------------------------------
template <int BM, int MODE>
__device__ __forceinline__ void gemm_body(
    const unsigned short* __restrict__ A, const unsigned short* __restrict__ Bt,
    void* __restrict__ Cout, const float* __restrict__ resid) {
  constexpr int MF = BM / 32;            // m-frags per wave (4 or 2)
  constexpr int ATILE = BM * 64;         // bytes per A buffer (8K or 4K)
  __shared__ __align__(16) char sm[2 * ATILE + 16384];
  int t = threadIdx.x;
  int bn = blockIdx.x, bm = blockIdx.y;
  int m0 = bm * BM, n0 = bn * 128;
  int lane = t & 63, w = t >> 6, lr = lane & 15, lg = lane >> 4;
  int wr = w >> 1, wc = w & 1;

  f32x4 acc[MF][4] = {};

  const char* aA = (const char*)A + ((size_t)(m0 + (t >> 2)) * 1024 + (t & 3) * 8) * 2;
  const char* aB = (const char*)Bt + ((size_t)(n0 + (t >> 2)) * 1024 + (t & 3) * 8) * 2;

  auto stage = [&](int buf, int kt) {
    int koff = kt * 64;  // bytes into the K dimension
    char* As = sm + buf * ATILE;
    char* Bs = sm + 2 * ATILE + buf * 8192;
#pragma unroll
    for (int c = 0; c < BM / 64; ++c)
      gload16(aA + (size_t)c * 131072 + koff, As + c * 4096 + t * 16);
#pragma unroll
    for (int c = 0; c < 2; ++c)
      gload16(aB + (size_t)c * 131072 + koff, Bs + c * 4096 + t * 16);
  };

  stage(0, 0);
  __syncthreads();
  int cur = 0;
  for (int kt = 0; kt < 32; ++kt) {
    if (kt < 31) stage(cur ^ 1, kt + 1);
    const char* As = sm + cur * ATILE;
    const char* Bs = sm + 2 * ATILE + cur * 8192;
    s16x8 af[MF], bfr[4];
#pragma unroll
    for (int m = 0; m < MF; ++m)
      af[m] = *reinterpret_cast<const s16x8*>(
          As + (wr * (BM / 2) + m * 16 + lr) * 64 + lg * 16);
#pragma unroll
    for (int n = 0; n < 4; ++n)
      bfr[n] = *reinterpret_cast<const s16x8*>(
          Bs + (wc * 64 + n * 16 + lr) * 64 + lg * 16);
#pragma unroll
    for (int m = 0; m < MF; ++m)
#pragma unroll
      for (int n = 0; n < 4; ++n)
        acc[m][n] = __builtin_amdgcn_mfma_f32_16x16x32_bf16(af[m], bfr[n], acc[m][n], 0, 0, 0);
    asm volatile("s_waitcnt vmcnt(0)" ::: "memory");
    __builtin_amdgcn_s_barrier();
    cur ^= 1;
  }

#pragma unroll
  for (int m = 0; m < MF; ++m)
#pragma unroll
    for (int n = 0; n < 4; ++n) {
      int colg = n0 + wc * 64 + n * 16 + lr;
      int rowb = m0 + wr * (BM / 2) + m * 16 + lg * 4;
      if (MODE == 0) {
        unsigned short* C = (unsigned short*)Cout;
#pragma unroll
        for (int r = 0; r < 4; ++r)
          C[(size_t)(rowb + r) * 1024 + colg] = f2bf(acc[m][n][r]);
      } else if (MODE == 1) {
        int h = colg >> 6, d = colg & 63;
        int b = rowb >> 11, kv = rowb & 2047;
        unsigned short* C = (unsigned short*)Cout +
            ((size_t)((b * 16 + h) * 64 + d) * 2048 + kv);
        unsigned int lo = (unsigned int)f2bf(acc[m][n][0]) |
                          ((unsigned int)f2bf(acc[m][n][1]) << 16);
        unsigned int hi = (unsigned int)f2bf(acc[m][n][2]) |
                          ((unsigned int)f2bf(acc[m][n][3]) << 16);
        uint2 pk2; pk2.x = lo; pk2.y = hi;
        *reinterpret_cast<uint2*>(C) = pk2;
      } else {
        float* C = (float*)Cout;
#pragma unroll
        for (int r = 0; r < 4; ++r) {
          size_t idx = (size_t)(rowb + r) * 1024 + colg;
          C[idx] = resid[idx] + acc[m][n][r];
        }
      }
    }
}

__global__ __launch_bounds__(256, 4) void k_gemm_qkv(
    const unsigned short* __restrict__ normed, const unsigned short* __restrict__ kvb,
    const unsigned short* __restrict__ wqT, const unsigned short* __restrict__ wkT,
    const unsigned short* __restrict__ wvT,
    unsigned short* __restrict__ qb, unsigned short* __restrict__ kb,
    unsigned short* __restrict__ vTb) {
  int z = blockIdx.z;
  const unsigned short* A = (z == 0) ? normed : kvb;
  const unsigned short* B = (z == 0) ? wqT : (z == 1) ? wkT : wvT;
  if (z == 2)
    gemm_body<128, 1>(A, B, (void*)vTb, nullptr);
  else if (z == 1)
    gemm_body<128, 0>(A, B, (void*)kb, nullptr);
  else
    gemm_body<128, 0>(A, B, (void*)qb, nullptr);
}

__global__ __launch_bounds__(256, 4) void k_gemm_o(
    const unsigned short* __restrict__ ctxb, const unsigned short* __restrict__ woT,
    float* __restrict__ out, const float* __restrict__ hs) {
  gemm_body<64, 2>(ctxb, woT, (void*)out, hs);
}

// ---------------------------------------------------------------------------
// Flash attention, round 9.  KVBLK=64, 32 iters, LDS 32KB -> 4 blocks/CU.
// Grid: 512 blocks 1D (XCD-clustered); block 256 = 4 waves; wave owns 32 q.
// LDS: Ks dbuf 2x8K | Vs dbuf 2x8K.
// Swapped QK^T -> in-register P (zero shuffles), kv-permuted PV (round 8).
// ---------------------------------------------------------------------------
__global__ __launch_bounds__(256, 4) void k_attn(
    const unsigned short* __restrict__ q, const unsigned short* __restrict__ k,
    const unsigned short* __restrict__ vt, unsigned short* __restrict__ ctx) {
  __shared__ __align__(16) char sm[32768];
  // Ks0 @0, Ks1 @8K, Vs0 @16K, Vs1 @24K
  int t = threadIdx.x, w = t >> 6, lane = t & 63, lr = lane & 15, lg = lane >> 4;

  // XCD-aware decomposition: 64 consecutive-slot blocks per XCD = 4 heads
  int bid = blockIdx.x;
  int xcd = bid & 7, slot = bid >> 3;
  int bh = xcd * 4 + (slot >> 4);   // [0,32)
  int qt = slot & 15;               // [0,16)
  int b = bh >> 4, h = bh & 15;

  const char* qB = (const char*)q + ((size_t)(b * 2048 + qt * 128) * 1024 + h * 64) * 2;
  const char* kB = (const char*)k + ((size_t)(b * 2048) * 1024 + h * 64) * 2;
  const char* vB = (const char*)vt + (size_t)bh * 64 * 4096;

  // staging geometry (pre-unswizzled sources; dest is lane-linear)
  int srow = t >> 3;                               // [0,32)
  int scb  = ((t & 7) * 16) ^ ((srow & 7) << 4);   // swizzled 16B chunk in row

  auto stageKV = [&](int buf, int it2) {
    char* Kd = sm + buf * 8192;
    char* Vd = sm + 16384 + buf * 8192;
    const char* kb2 = kB + (size_t)(it2 * 64) * 2048;
    const char* vb2 = vB + it2 * 128;
#pragma unroll
    for (int c = 0; c < 2; ++c) {
      gload16(kb2 + (size_t)(c * 32 + srow) * 2048 + scb, Kd + c * 4096 + t * 16);
      gload16(vb2 + (size_t)(c * 32 + srow) * 4096 + scb, Vd + c * 4096 + t * 16);
    }
  };

  // ---- prologue: stage Q [128 rows][128B] into whole sm, read frags
#pragma unroll
  for (int c = 0; c < 4; ++c)
    gload16(qB + (size_t)(c * 32 + srow) * 2048 + scb, sm + c * 4096 + t * 16);
  __syncthreads();
  s16x8 qa[2][2];
#pragma unroll
  for (int mm = 0; mm < 2; ++mm)
#pragma unroll
    for (int ks = 0; ks < 2; ++ks) {
      int row = w * 32 + mm * 16 + lr;
      qa[mm][ks] = *reinterpret_cast<const s16x8*>(
          sm + row * 128 + ((ks * 64 + lg * 16) ^ ((lr & 7) << 4)));
    }
  __syncthreads();  // all q-frag reads done before staging overwrites sm
  stageKV(0, 0);
  asm volatile("s_waitcnt vmcnt(0)" ::: "memory");
  __builtin_amdgcn_s_barrier();
  __builtin_amdgcn_sched_barrier(0);

  f32x4 octx[2][4] = {};
  float mrun[2] = {-1e30f, -1e30f};
  float lsum[2] = {0.0f, 0.0f};

  int cur = 0;
  for (int it = 0; it < 32; ++it) {
    // ---- issue next tile's staging (completes under this iter's compute)
    if (it < 31) stageKV(cur ^ 1, it + 1);

    const char* Ks = sm + cur * 8192;
    const char* Vs = sm + 16384 + cur * 8192;

    // ---- S^T = K Q^T (swapped): lane holds S[q=lr][kv=n*16+lg*4+r]
    f32x4 s2[2][4] = {};
#pragma unroll
    for (int ks = 0; ks < 2; ++ks) {
      s16x8 ka[4];
#pragma unroll
      for (int n = 0; n < 4; ++n)
        ka[n] = *reinterpret_cast<const s16x8*>(
            Ks + (n * 16 + lr) * 128 + ((ks * 64 + lg * 16) ^ ((lr & 7) << 4)));
#pragma unroll
      for (int mm = 0; mm < 2; ++mm)
#pragma unroll
        for (int n = 0; n < 4; ++n)
          s2[mm][n] = __builtin_amdgcn_mfma_f32_16x16x32_bf16(ka[n], qa[mm][ks], s2[mm][n], 0, 0, 0);
    }

    // ---- online softmax (per-lane row stats; reduce across lg groups)
    float m2[2];
#pragma unroll
    for (int mm = 0; mm < 2; ++mm) {
      float v = s2[mm][0][0];
#pragma unroll
      for (int n = 0; n < 4; ++n)
#pragma unroll
        for (int r = 0; r < 4; ++r) v = fmaxf(v, s2[mm][n][r]);
      v = fmaxf(v, __shfl_xor(v, 16));
      v = fmaxf(v, __shfl_xor(v, 32));
      m2[mm] = v;
    }
    int need = (m2[0] > mrun[0] + 8.0f) || (m2[1] > mrun[1] + 8.0f);
    if (__any(need)) {
#pragma unroll
      for (int mm = 0; mm < 2; ++mm) {
        float mx = fmaxf(mrun[mm], m2[mm]);
        float sc = EXP2(mrun[mm] - mx);
        mrun[mm] = mx;
        lsum[mm] *= sc;
#pragma unroll
        for (int r = 0; r < 4; ++r) {
          float scr = __shfl(sc, lg * 4 + r);
#pragma unroll
          for (int nd = 0; nd < 4; ++nd) octx[mm][nd][r] *= scr;
        }
      }
    }

    // ---- exp2 + in-register bf16 pack (lane-local; zero cross-lane moves)
    unsigned pk[2][4][2];
#pragma unroll
    for (int mm = 0; mm < 2; ++mm) {
      float a0 = 0.0f, a1 = 0.0f, a2 = 0.0f, a3 = 0.0f;
#pragma unroll
      for (int n = 0; n < 4; ++n) {
        float p0 = EXP2(s2[mm][n][0] - mrun[mm]);
        float p1 = EXP2(s2[mm][n][1] - mrun[mm]);
        float p2 = EXP2(s2[mm][n][2] - mrun[mm]);
        float p3 = EXP2(s2[mm][n][3] - mrun[mm]);
        a0 += p0; a1 += p1; a2 += p2; a3 += p3;
        pk[mm][n][0] = cvtpk(p0, p1);
        pk[mm][n][1] = cvtpk(p2, p3);
      }
      lsum[mm] += (a0 + a1) + (a2 + a3);
    }

    // ---- PV with permuted kv order (A = own pk regs; B = matching V cols)
#pragma unroll
    for (int ks = 0; ks < 2; ++ks) {
      s16x8 vb[4];
#pragma unroll
      for (int nd = 0; nd < 4; ++nd) {
        int row = nd * 16 + lr;
        int swz = (lr & 7) << 4;
        uint2 v1 = *reinterpret_cast<const uint2*>(
            Vs + row * 128 + ((ks * 64 + lg * 8) ^ swz));
        uint2 v2 = *reinterpret_cast<const uint2*>(
            Vs + row * 128 + ((ks * 64 + 32 + lg * 8) ^ swz));
        i32x4 vv; vv[0] = (int)v1.x; vv[1] = (int)v1.y;
        vv[2] = (int)v2.x; vv[3] = (int)v2.y;
        vb[nd] = __builtin_bit_cast(s16x8, vv);
      }
#pragma unroll
      for (int mm = 0; mm < 2; ++mm) {
        i32x4 pv;
        pv[0] = (int)pk[mm][2 * ks][0];     pv[1] = (int)pk[mm][2 * ks][1];
        pv[2] = (int)pk[mm][2 * ks + 1][0]; pv[3] = (int)pk[mm][2 * ks + 1][1];
        s16x8 pa = __builtin_bit_cast(s16x8, pv);
#pragma unroll
        for (int nd = 0; nd < 4; ++nd)
          octx[mm][nd] = __builtin_amdgcn_mfma_f32_16x16x32_bf16(pa, vb[nd], octx[mm][nd], 0, 0, 0);
      }
    }

    // ---- drain this iter's prefetch, then release buffers
    if (it < 31) {
      asm volatile("s_waitcnt vmcnt(0)" ::: "memory");
      __builtin_amdgcn_s_barrier();
      __builtin_amdgcn_sched_barrier(0);
      cur ^= 1;
    }
  }

  // ---- epilogue: reduce lsum across lg, normalize, store bf16
#pragma unroll
  for (int mm = 0; mm < 2; ++mm) {
    float tot = lsum[mm];
    tot += __shfl_xor(tot, 16);
    tot += __shfl_xor(tot, 32);
    float inv = 1.0f / tot;
#pragma unroll
    for (int r = 0; r < 4; ++r) {
      float invr = __shfl(inv, lg * 4 + r);
      int qrow = qt * 128 + w * 32 + mm * 16 + lg * 4 + r;
#pragma unroll
      for (int nd = 0; nd < 4; ++nd)
        ctx[(size_t)(b * 2048 + qrow) * 1024 + h * 64 + nd * 16 + lr] =
            f2bf(octx[mm][nd][r] * invr);
    }
  }
}

// ---------------------------------------------------------------------------
// Launch
// ---------------------------------------------------------------------------
extern "C" void kernel_launch(void* const* d_in, const int* in_sizes, int n_in,
                              void* d_out, int out_size, void* d_ws, size_t ws_size,
                              hipStream_t stream) {
  const float* hs  = (const float*)d_in[0];
  const float* kvs = (const float*)d_in[1];
  const float* wq  = (const float*)d_in[2];
  const float* wk  = (const float*)d_in[3];
  const float* wv  = (const float*)d_in[4];
  const float* wo  = (const float*)d_in[5];
  const float* nw  = (const float*)d_in[6];
  float* out = (float*)d_out;
  char* ws = (char*)d_ws;

  unsigned short* normed = (unsigned short*)(ws + (size_t)0);
  unsigned short* kvb    = (unsigned short*)(ws + ((size_t)8 << 20));
  unsigned short* wqT    = (unsigned short*)(ws + ((size_t)16 << 20));
  unsigned short* wkT    = (unsigned short*)(ws + ((size_t)18 << 20));
  unsigned short* wvT    = (unsigned short*)(ws + ((size_t)20 << 20));
  unsigned short* woT    = (unsigned short*)(ws + ((size_t)22 << 20));
  unsigned short* qb     = (unsigned short*)(ws + ((size_t)24 << 20));
  unsigned short* kb     = (unsigned short*)(ws + ((size_t)32 << 20));
  unsigned short* vTb    = (unsigned short*)(ws + ((size_t)40 << 20));
  unsigned short* ctxb   = (unsigned short*)(ws + ((size_t)48 << 20));

  k_transpose4<<<dim3(16, 16, 4), 256, 0, stream>>>(wq, wk, wv, wo, wqT, wkT, wvT, woT);
  k_rmsnorm<<<4096, 256, 0, stream>>>(hs, nw, normed);
  k_cast<<<1024, 256, 0, stream>>>(kvs, kvb, 1048576);

  k_gemm_qkv<<<dim3(8, 32, 3), 256, 0, stream>>>(normed, kvb, wqT, wkT, wvT, qb, kb, vTb);

  k_attn<<<512, 256, 0, stream>>>(qb, kb, vTb, ctxb);

  k_gemm_o<<<dim3(8, 64), 256, 0, stream>>>(ctxb, woT, out, hs);
}

// Round 10
// 141.896 us; speedup vs baseline: 1.1603x; 1.1603x over previous
//
#include <hip/hip_runtime.h>

// ---------------------------------------------------------------------------
// T5 cross-attention fused pipeline for MI355X (gfx950)  — round 10
// B=2, Q=KV=2048, D_MODEL=1024, H=16, D=64
// Round 9 regressed (grid-capped occupancy, doubled barrier overhead).
// Round 10 = round-8 structures + attn 512-thread blocks (8 waves x 16 q-rows,
// same grid, 2x waves/CU) to raise occupancy at fixed 512-block grid.
// ---------------------------------------------------------------------------

typedef __attribute__((ext_vector_type(8))) short  s16x8;   // 8 bf16 (A/B frag)
typedef __attribute__((ext_vector_type(4))) float  f32x4;   // C/D frag
typedef __attribute__((ext_vector_type(4))) int    i32x4;

#define LOG2E 1.4426950408889634f
#define EXP2(x) __builtin_amdgcn_exp2f(x)

__device__ __forceinline__ unsigned short f2bf(float f) {
  unsigned int u = __builtin_bit_cast(unsigned int, f);
  return (unsigned short)((u + 0x7FFFu + ((u >> 16) & 1u)) >> 16);  // RNE
}

__device__ __forceinline__ unsigned cvtpk(float lo, float hi) {
  unsigned r;
  asm("v_cvt_pk_bf16_f32 %0, %1, %2" : "=v"(r) : "v"(lo), "v"(hi));
  return r;
}

__device__ __forceinline__ void gload16(const void* g, void* l) {
  __builtin_amdgcn_global_load_lds(
      (const __attribute__((address_space(1))) unsigned int*)g,
      (__attribute__((address_space(3))) unsigned int*)l, 16, 0, 0);
}

// ---------------------------------------------------------------------------
// Transpose-cast x4 in one dispatch: out[n][k] = bf16(in[k][n]), 1024x1024
// ---------------------------------------------------------------------------
__global__ __launch_bounds__(256) void k_transpose4(
    const float* __restrict__ a0, const float* __restrict__ a1,
    const float* __restrict__ a2, const float* __restrict__ a3,
    unsigned short* __restrict__ o0, unsigned short* __restrict__ o1,
    unsigned short* __restrict__ o2, unsigned short* __restrict__ o3) {
  int z = blockIdx.z;
  const float* in = (z == 0) ? a0 : (z == 1) ? a1 : (z == 2) ? a2 : a3;
  unsigned short* out = (z == 0) ? o0 : (z == 1) ? o1 : (z == 2) ? o2 : o3;
  __shared__ float tile[64][65];
  int t = threadIdx.x;
  int tx = t & 15, ty = t >> 4;
  int r0 = blockIdx.y * 64, c0 = blockIdx.x * 64;
#pragma unroll
  for (int p = 0; p < 4; ++p) {
    int r = p * 16 + ty;
    float4 v = *reinterpret_cast<const float4*>(in + (size_t)(r0 + r) * 1024 + c0 + tx * 4);
    tile[r][tx * 4 + 0] = v.x; tile[r][tx * 4 + 1] = v.y;
    tile[r][tx * 4 + 2] = v.z; tile[r][tx * 4 + 3] = v.w;
  }
  __syncthreads();
#pragma unroll
  for (int p = 0; p < 4; ++p) {
    int c = p * 16 + ty;
    unsigned int lo = (unsigned int)f2bf(tile[tx * 4 + 0][c]) |
                      ((unsigned int)f2bf(tile[tx * 4 + 1][c]) << 16);
    unsigned int hi = (unsigned int)f2bf(tile[tx * 4 + 2][c]) |
                      ((unsigned int)f2bf(tile[tx * 4 + 3][c]) << 16);
    uint2 pk2; pk2.x = lo; pk2.y = hi;
    *reinterpret_cast<uint2*>(out + (size_t)(c0 + c) * 1024 + r0 + tx * 4) = pk2;
  }
}

// ---------------------------------------------------------------------------
// RMSNorm + cast to bf16, scaled by log2(e) (feeds ONLY the Q projection ->
// QK^T scores land in the exp2 domain for free).
// ---------------------------------------------------------------------------
__global__ __launch_bounds__(256) void k_rmsnorm(
    const float* __restrict__ hs, const float* __restrict__ w,
    unsigned short* __restrict__ out) {
  int row = blockIdx.x, t = threadIdx.x;
  float4 v = *reinterpret_cast<const float4*>(hs + (size_t)row * 1024 + t * 4);
  float s = v.x * v.x + v.y * v.y + v.z * v.z + v.w * v.w;
#pragma unroll
  for (int m = 1; m < 64; m <<= 1) s += __shfl_xor(s, m);
  __shared__ float ps[4];
  if ((t & 63) == 0) ps[t >> 6] = s;
  __syncthreads();
  float tot = ps[0] + ps[1] + ps[2] + ps[3];
  float sc = rsqrtf(tot * (1.0f / 1024.0f) + 1e-6f) * LOG2E;
  float4 wv = *reinterpret_cast<const float4*>(w + t * 4);
  unsigned int lo = (unsigned int)f2bf(v.x * sc * wv.x) |
                    ((unsigned int)f2bf(v.y * sc * wv.y) << 16);
  unsigned int hi = (unsigned int)f2bf(v.z * sc * wv.z) |
                    ((unsigned int)f2bf(v.w * sc * wv.w) << 16);
  uint2 pk2; pk2.x = lo; pk2.y = hi;
  *reinterpret_cast<uint2*>(out + (size_t)row * 1024 + t * 4) = pk2;
}

// ---------------------------------------------------------------------------
// Plain f32 -> bf16 cast
// ---------------------------------------------------------------------------
__global__ __launch_bounds__(256) void k_cast(
    const float* __restrict__ in, unsigned short* __restrict__ out, int n4) {
  int i = blockIdx.x * 256 + threadIdx.x;
  int stride = gridDim.x * 256;
  for (; i < n4; i += stride) {
    float4 v = *reinterpret_cast<const float4*>(in + (size_t)i * 4);
    unsigned int lo = (unsigned int)f2bf(v.x) | ((unsigned int)f2bf(v.y) << 16);
    unsigned int hi = (unsigned int)f2bf(v.z) | ((unsigned int)f2bf(v.w) << 16);
    uint2 pk2; pk2.x = lo; pk2.y = hi;
    *reinterpret_cast<uint2*>(out + (size_t)i * 4) = pk2;
  }
}

// ---------------------------------------------------------------------------
// GEMM body (round-8 proven): C[M,N] = A[M,K] * Bt[N,K]^T
// (M=4096, N=1024, K=1024, bf16). 128x128 tile, BK=64, dbuf, 2-phase.
// mode 0: bf16 out; mode 1: bf16 out transposed to vT [b][h][d][2048];
// mode 2: f32 out + residual
// ---------------------------------------------------------------------------
__device__ __forceinline__ void gemm_body(
    const unsigned short* __restrict__ A, const unsigned short* __restrict__ Bt,
    void* __restrict__ Cout, const float* __restrict__ resid, int mode) {
  __shared__ __align__(16) char sm[65536];
  int t = threadIdx.x;
  int bn = blockIdx.x, bm = blockIdx.y;
  int m0 = bm * 128, n0 = bn * 128;
  int lane = t & 63, w = t >> 6, lr = lane & 15, lg = lane >> 4;
  int wr = w >> 1, wc = w & 1;

  f32x4 acc[4][4] = {};

  const char* aA = (const char*)A + ((size_t)(m0 + (t >> 3)) * 1024 + (t & 7) * 8) * 2;
  const char* aB = (const char*)Bt + ((size_t)(n0 + (t >> 3)) * 1024 + (t & 7) * 8) * 2;

  auto stage = [&](int buf, int kt) {
    int koff = kt * 128;  // bytes into the K dimension
    char* As = sm + buf * 16384;
    char* Bs = sm + 32768 + buf * 16384;
#pragma unroll
    for (int c = 0; c < 4; ++c) {
      gload16(aA + (size_t)c * 65536 + koff, As + c * 4096 + t * 16);
      gload16(aB + (size_t)c * 65536 + koff, Bs + c * 4096 + t * 16);
    }
  };

  stage(0, 0);
  __syncthreads();
  int cur = 0;
  for (int kt = 0; kt < 16; ++kt) {
    if (kt < 15) stage(cur ^ 1, kt + 1);
    const char* As = sm + cur * 16384;
    const char* Bs = sm + 32768 + cur * 16384;
    s16x8 af[2][4], bfr[2][4];
#pragma unroll
    for (int ks = 0; ks < 2; ++ks) {
#pragma unroll
      for (int m = 0; m < 4; ++m)
        af[ks][m] = *reinterpret_cast<const s16x8*>(
            As + (wr * 64 + m * 16 + lr) * 128 + ks * 64 + lg * 16);
#pragma unroll
      for (int n = 0; n < 4; ++n)
        bfr[ks][n] = *reinterpret_cast<const s16x8*>(
            Bs + (wc * 64 + n * 16 + lr) * 128 + ks * 64 + lg * 16);
    }
#pragma unroll
    for (int ks = 0; ks < 2; ++ks)
#pragma unroll
      for (int m = 0; m < 4; ++m)
#pragma unroll
        for (int n = 0; n < 4; ++n)
          acc[m][n] = __builtin_amdgcn_mfma_f32_16x16x32_bf16(af[ks][m], bfr[ks][n], acc[m][n], 0, 0, 0);
    __syncthreads();
    cur ^= 1;
  }

#pragma unroll
  for (int m = 0; m < 4; ++m)
#pragma unroll
    for (int n = 0; n < 4; ++n) {
      int colg = n0 + wc * 64 + n * 16 + lr;
      int rowb = m0 + wr * 64 + m * 16 + lg * 4;
      if (mode == 0) {
        unsigned short* C = (unsigned short*)Cout;
#pragma unroll
        for (int r = 0; r < 4; ++r)
          C[(size_t)(rowb + r) * 1024 + colg] = f2bf(acc[m][n][r]);
      } else if (mode == 1) {
        int h = colg >> 6, d = colg & 63;
        int b = rowb >> 11, kv = rowb & 2047;
        unsigned short* C = (unsigned short*)Cout +
            ((size_t)((b * 16 + h) * 64 + d) * 2048 + kv);
        unsigned int lo = (unsigned int)f2bf(acc[m][n][0]) |
                          ((unsigned int)f2bf(acc[m][n][1]) << 16);
        unsigned int hi = (unsigned int)f2bf(acc[m][n][2]) |
                          ((unsigned int)f2bf(acc[m][n][3]) << 16);
        uint2 pk2; pk2.x = lo; pk2.y = hi;
        *reinterpret_cast<uint2*>(C) = pk2;
      } else {
        float* C = (float*)Cout;
#pragma unroll
        for (int r = 0; r < 4; ++r) {
          size_t idx = (size_t)(rowb + r) * 1024 + colg;
          C[idx] = resid[idx] + acc[m][n][r];
        }
      }
    }
}

__global__ __launch_bounds__(256) void k_gemm_qkv(
    const unsigned short* __restrict__ normed, const unsigned short* __restrict__ kvb,
    const unsigned short* __restrict__ wqT, const unsigned short* __restrict__ wkT,
    const unsigned short* __restrict__ wvT,
    unsigned short* __restrict__ qb, unsigned short* __restrict__ kb,
    unsigned short* __restrict__ vTb) {
  int z = blockIdx.z;
  const unsigned short* A = (z == 0) ? normed : kvb;
  const unsigned short* B = (z == 0) ? wqT : (z == 1) ? wkT : wvT;
  void* C = (z == 0) ? (void*)qb : (z == 1) ? (void*)kb : (void*)vTb;
  gemm_body(A, B, C, nullptr, (z == 2) ? 1 : 0);
}

__global__ __launch_bounds__(256) void k_gemm_o(
    const unsigned short* __restrict__ ctxb, const unsigned short* __restrict__ woT,
    float* __restrict__ out, const float* __restrict__ hs) {
  gemm_body(ctxb, woT, (void*)out, hs, 2);
}

// ---------------------------------------------------------------------------
// Flash attention, round 10.
// Grid: 512 blocks 1D (XCD-clustered); block 512 = 8 waves; wave owns 16 q.
// LDS (64KB): Ks dbuf 2x16K | Vs dbuf 2x16K.  KVBLK=128, 16 iters.
// Swapped QK^T -> in-register P (zero shuffles), kv-permuted PV (round 8).
// 8 waves give 16 waves/CU at 2 blocks/CU (2x round-8 TLP).
// ---------------------------------------------------------------------------
__global__ __launch_bounds__(512, 4) void k_attn(
    const unsigned short* __restrict__ q, const unsigned short* __restrict__ k,
    const unsigned short* __restrict__ vt, unsigned short* __restrict__ ctx) {
  __shared__ __align__(16) char sm[65536];
  // Ks0 @0, Ks1 @16K, Vs0 @32K, Vs1 @48K
  int t = threadIdx.x, w = t >> 6, lane = t & 63, lr = lane & 15, lg = lane >> 4;

  // XCD-aware decomposition: 64 consecutive-slot blocks per XCD = 4 heads
  int bid = blockIdx.x;
  int xcd = bid & 7, slot = bid >> 3;
  int bh = xcd * 4 + (slot >> 4);   // [0,32)
  int qt = slot & 15;               // [0,16)
  int b = bh >> 4, h = bh & 15;

  const char* qB = (const char*)q + ((size_t)(b * 2048 + qt * 128) * 1024 + h * 64) * 2;
  const char* kB = (const char*)k + ((size_t)(b * 2048) * 1024 + h * 64) * 2;
  const char* vB = (const char*)vt + (size_t)bh * 64 * 4096;

  // staging geometry (pre-unswizzled sources; dest is lane-linear, 512 thr)
  int krow = t >> 3;                               // [0,64) K/Q row per round
  int kcb  = ((t & 7) * 16) ^ ((krow & 7) << 4);
  int vrow = t >> 4;                               // [0,32) V row per round
  int vcb  = ((t & 15) * 16) ^ ((vrow & 7) << 4);

  auto stageKV = [&](int buf, int it2) {
    char* Kd = sm + buf * 16384;
    char* Vd = sm + 32768 + buf * 16384;
    const char* kb2 = kB + (size_t)(it2 * 128) * 2048;
    const char* vb2 = vB + it2 * 256;
#pragma unroll
    for (int c = 0; c < 2; ++c) {
      gload16(kb2 + (size_t)(c * 64 + krow) * 2048 + kcb, Kd + c * 8192 + t * 16);
      gload16(vb2 + (size_t)(c * 32 + vrow) * 4096 + vcb, Vd + c * 8192 + t * 16);
    }
  };

  // ---- prologue: stage Q [128 rows][128B] into Ks0 area, read frags
#pragma unroll
  for (int c = 0; c < 2; ++c)
    gload16(qB + (size_t)(c * 64 + krow) * 2048 + kcb, sm + c * 8192 + t * 16);
  __syncthreads();
  s16x8 qa[2];
#pragma unroll
  for (int ks = 0; ks < 2; ++ks) {
    int row = w * 16 + lr;
    qa[ks] = *reinterpret_cast<const s16x8*>(
        sm + row * 128 + ((ks * 64 + lg * 16) ^ ((lr & 7) << 4)));
  }
  __syncthreads();  // all q-frag reads done before staging overwrites Ks0
  stageKV(0, 0);
  asm volatile("s_waitcnt vmcnt(0)" ::: "memory");
  __builtin_amdgcn_s_barrier();
  __builtin_amdgcn_sched_barrier(0);

  f32x4 octx[4] = {};
  float mrun = -1e30f;
  float lsum = 0.0f;

  int cur = 0;
  for (int it = 0; it < 16; ++it) {
    // ---- issue next tile's staging (completes under this iter's compute)
    if (it < 15) stageKV(cur ^ 1, it + 1);

    const char* Ks = sm + cur * 16384;
    const char* Vs = sm + 32768 + cur * 16384;

    // ---- S^T = K Q^T (swapped): lane holds S[q=lr][kv=n*16+lg*4+r]
    f32x4 s2[8] = {};
#pragma unroll
    for (int ks = 0; ks < 2; ++ks) {
      s16x8 ka[8];
#pragma unroll
      for (int n = 0; n < 8; ++n)
        ka[n] = *reinterpret_cast<const s16x8*>(
            Ks + (n * 16 + lr) * 128 + ((ks * 64 + lg * 16) ^ ((lr & 7) << 4)));
#pragma unroll
      for (int n = 0; n < 8; ++n)
        s2[n] = __builtin_amdgcn_mfma_f32_16x16x32_bf16(ka[n], qa[ks], s2[n], 0, 0, 0);
    }

    // ---- online softmax (per-lane row stats; reduce across lg groups)
    float m2 = s2[0][0];
#pragma unroll
    for (int n = 0; n < 8; ++n)
#pragma unroll
      for (int r = 0; r < 4; ++r) m2 = fmaxf(m2, s2[n][r]);
    m2 = fmaxf(m2, __shfl_xor(m2, 16));
    m2 = fmaxf(m2, __shfl_xor(m2, 32));
    if (__any(m2 > mrun + 8.0f)) {
      float mx = fmaxf(mrun, m2);
      float sc = EXP2(mrun - mx);
      mrun = mx;
      lsum *= sc;
#pragma unroll
      for (int r = 0; r < 4; ++r) {
        float scr = __shfl(sc, lg * 4 + r);
#pragma unroll
        for (int nd = 0; nd < 4; ++nd) octx[nd][r] *= scr;
      }
    }

    // ---- exp2 + in-register bf16 pack (lane-local; zero cross-lane moves)
    unsigned pk[8][2];
    {
      float a0 = 0.0f, a1 = 0.0f, a2 = 0.0f, a3 = 0.0f;
#pragma unroll
      for (int n = 0; n < 8; ++n) {
        float p0 = EXP2(s2[n][0] - mrun);
        float p1 = EXP2(s2[n][1] - mrun);
        float p2 = EXP2(s2[n][2] - mrun);
        float p3 = EXP2(s2[n][3] - mrun);
        a0 += p0; a1 += p1; a2 += p2; a3 += p3;
        pk[n][0] = cvtpk(p0, p1);
        pk[n][1] = cvtpk(p2, p3);
      }
      lsum += (a0 + a1) + (a2 + a3);
    }

    // ---- PV with permuted kv order (A = own pk regs; B = matching V cols)
#pragma unroll
    for (int ks = 0; ks < 4; ++ks) {
      s16x8 vb[4];
#pragma unroll
      for (int nd = 0; nd < 4; ++nd) {
        int row = nd * 16 + lr;
        int swz = (lr & 7) << 4;
        uint2 v1 = *reinterpret_cast<const uint2*>(
            Vs + row * 256 + ((ks * 64 + lg * 8) ^ swz));
        uint2 v2 = *reinterpret_cast<const uint2*>(
            Vs + row * 256 + ((ks * 64 + 32 + lg * 8) ^ swz));
        i32x4 vv; vv[0] = (int)v1.x; vv[1] = (int)v1.y;
        vv[2] = (int)v2.x; vv[3] = (int)v2.y;
        vb[nd] = __builtin_bit_cast(s16x8, vv);
      }
      i32x4 pv;
      pv[0] = (int)pk[2 * ks][0];     pv[1] = (int)pk[2 * ks][1];
      pv[2] = (int)pk[2 * ks + 1][0]; pv[3] = (int)pk[2 * ks + 1][1];
      s16x8 pa = __builtin_bit_cast(s16x8, pv);
#pragma unroll
      for (int nd = 0; nd < 4; ++nd)
        octx[nd] = __builtin_amdgcn_mfma_f32_16x16x32_bf16(pa, vb[nd], octx[nd], 0, 0, 0);
    }

    // ---- drain this iter's prefetch, then release buffers
    if (it < 15) {
      asm volatile("s_waitcnt vmcnt(0)" ::: "memory");
      __builtin_amdgcn_s_barrier();
      __builtin_amdgcn_sched_barrier(0);
      cur ^= 1;
    }
  }

  // ---- epilogue: reduce lsum across lg, normalize, store bf16
  {
    float tot = lsum;
    tot += __shfl_xor(tot, 16);
    tot += __shfl_xor(tot, 32);
    float inv = 1.0f / tot;
#pragma unroll
    for (int r = 0; r < 4; ++r) {
      float invr = __shfl(inv, lg * 4 + r);
      int qrow = qt * 128 + w * 16 + lg * 4 + r;
#pragma unroll
      for (int nd = 0; nd < 4; ++nd)
        ctx[(size_t)(b * 2048 + qrow) * 1024 + h * 64 + nd * 16 + lr] =
            f2bf(octx[nd][r] * invr);
    }
  }
}

// ---------------------------------------------------------------------------
// Launch
// ---------------------------------------------------------------------------
extern "C" void kernel_launch(void* const* d_in, const int* in_sizes, int n_in,
                              void* d_out, int out_size, void* d_ws, size_t ws_size,
                              hipStream_t stream) {
  const float* hs  = (const float*)d_in[0];
  const float* kvs = (const float*)d_in[1];
  const float* wq  = (const float*)d_in[2];
  const float* wk  = (const float*)d_in[3];
  const float* wv  = (const float*)d_in[4];
  const float* wo  = (const float*)d_in[5];
  const float* nw  = (const float*)d_in[6];
  float* out = (float*)d_out;
  char* ws = (char*)d_ws;

  unsigned short* normed = (unsigned short*)(ws + (size_t)0);
  unsigned short* kvb    = (unsigned short*)(ws + ((size_t)8 << 20));
  unsigned short* wqT    = (unsigned short*)(ws + ((size_t)16 << 20));
  unsigned short* wkT    = (unsigned short*)(ws + ((size_t)18 << 20));
  unsigned short* wvT    = (unsigned short*)(ws + ((size_t)20 << 20));
  unsigned short* woT    = (unsigned short*)(ws + ((size_t)22 << 20));
  unsigned short* qb     = (unsigned short*)(ws + ((size_t)24 << 20));
  unsigned short* kb     = (unsigned short*)(ws + ((size_t)32 << 20));
  unsigned short* vTb    = (unsigned short*)(ws + ((size_t)40 << 20));
  unsigned short* ctxb   = (unsigned short*)(ws + ((size_t)48 << 20));

  k_transpose4<<<dim3(16, 16, 4), 256, 0, stream>>>(wq, wk, wv, wo, wqT, wkT, wvT, woT);
  k_rmsnorm<<<4096, 256, 0, stream>>>(hs, nw, normed);
  k_cast<<<1024, 256, 0, stream>>>(kvs, kvb, 1048576);

  k_gemm_qkv<<<dim3(8, 32, 3), 256, 0, stream>>>(normed, kvb, wqT, wkT, wvT, qb, kb, vTb);

  k_attn<<<512, 512, 0, stream>>>(qb, kb, vTb, ctxb);

  k_gemm_o<<<dim3(8, 32), 256, 0, stream>>>(ctxb, woT, out, hs);
}